// Round 1
// 857.805 us; speedup vs baseline: 1.0168x; 1.0168x over previous
//
#include <hip/hip_runtime.h>

#define BATCH 8
#define CHANNELS 256
#define PLANE (256 * 256)   // H*W elements per (b,c) plane

typedef float f4 __attribute__((ext_vector_type(4)));

// ---------------------------------------------------------------------------
// Kernel 1: per-batch MLP + softmax gate.  grid = BATCH, block = CHANNELS.
// Thread c of block b computes channel c end-to-end.
// Softmax reductions are wave-level __shfl_xor (64-lane) + one 4-partial LDS
// combine each: 2 barriers total instead of 16 tree barriers (latency-bound
// kernel at 1 wave/SIMD occupancy -> barrier count dominates).
// Output: scale[b*C + c] = 1 + softmax(logits)[c]  (2048 floats).
// ---------------------------------------------------------------------------
__global__ __launch_bounds__(CHANNELS) void gate_kernel(
    const float* __restrict__ semantic,
    const float* __restrict__ W1,
    const float* __restrict__ b1,
    const float* __restrict__ W2,
    const float* __restrict__ b2,
    float* __restrict__ scale)
{
    const int b    = blockIdx.x;
    const int c    = threadIdx.x;
    const int lane = c & 63;
    const int wid  = c >> 6;          // 4 waves per block

    __shared__ float s_sem[CHANNELS];
    __shared__ float s_h[CHANNELS];
    __shared__ float s_max[4];
    __shared__ float s_sum[4];

    s_sem[c] = semantic[b * CHANNELS + c];
    __syncthreads();

    // h[c] = dot(semantic[b,:], W1[c,:]) + b1[c], LeakyReLU(0.1)
    float acc = b1[c];
    const float* w1row = W1 + (size_t)c * CHANNELS;
    #pragma unroll 4
    for (int k = 0; k < CHANNELS; k += 4) {
        float4 wv = *(const float4*)(w1row + k);
        acc += wv.x * s_sem[k]     + wv.y * s_sem[k + 1]
             + wv.z * s_sem[k + 2] + wv.w * s_sem[k + 3];
    }
    float h = acc > 0.0f ? acc : 0.1f * acc;
    s_h[c] = h;
    __syncthreads();

    // logits[c] = dot(h, W2[c,:]) + b2[c]
    float logit = b2[c];
    const float* w2row = W2 + (size_t)c * CHANNELS;
    #pragma unroll 4
    for (int k = 0; k < CHANNELS; k += 4) {
        float4 wv = *(const float4*)(w2row + k);
        logit += wv.x * s_h[k]     + wv.y * s_h[k + 1]
               + wv.z * s_h[k + 2] + wv.w * s_h[k + 3];
    }

    // ---- softmax over 256 channels: wave shfl reduce + 4-partial combine ----
    // max
    float m = logit;
    #pragma unroll
    for (int off = 32; off > 0; off >>= 1)
        m = fmaxf(m, __shfl_xor(m, off));
    if (lane == 0) s_max[wid] = m;
    __syncthreads();
    m = fmaxf(fmaxf(s_max[0], s_max[1]), fmaxf(s_max[2], s_max[3]));

    // sum of exp
    const float e = expf(logit - m);
    float s = e;
    #pragma unroll
    for (int off = 32; off > 0; off >>= 1)
        s += __shfl_xor(s, off);
    if (lane == 0) s_sum[wid] = s;
    __syncthreads();
    s = (s_sum[0] + s_sum[1]) + (s_sum[2] + s_sum[3]);

    scale[b * CHANNELS + c] = 1.0f + e / s;
}

// ---------------------------------------------------------------------------
// Kernel 2: out[b,c,:,:] = x[b,c,:,:] * scale[b,c].
// One block per (b,c) plane (2048 blocks = full residency at 8 blocks/CU);
// 16B coalesced accesses. Nontemporal hints: the 1.07 GB stream has zero
// reuse, so skip L3 write-allocate pollution (G14 / streaming-store idiom).
// scale[plane] is wave-uniform -> scalar load, no per-lane latency chain.
// ---------------------------------------------------------------------------
__global__ __launch_bounds__(256) void scale_kernel(
    const float* __restrict__ x,
    const float* __restrict__ scale,
    float* __restrict__ out)
{
    const int plane = blockIdx.x;             // 0 .. B*C-1
    const float s = scale[plane];

    const f4* __restrict__ xp = (const f4*)(x + (size_t)plane * PLANE);
    f4* __restrict__ op = (f4*)(out + (size_t)plane * PLANE);

    #pragma unroll 8
    for (int i = threadIdx.x; i < PLANE / 4; i += 256) {
        f4 v = __builtin_nontemporal_load(&xp[i]);
        v *= s;
        __builtin_nontemporal_store(v, &op[i]);
    }
}

extern "C" void kernel_launch(void* const* d_in, const int* in_sizes, int n_in,
                              void* d_out, int out_size, void* d_ws, size_t ws_size,
                              hipStream_t stream)
{
    const float* x        = (const float*)d_in[0];
    const float* semantic = (const float*)d_in[1];
    const float* W1       = (const float*)d_in[2];
    const float* b1       = (const float*)d_in[3];
    const float* W2       = (const float*)d_in[4];
    const float* b2       = (const float*)d_in[5];
    float* out   = (float*)d_out;
    float* scale = (float*)d_ws;   // B*C floats = 8 KB scratch

    gate_kernel<<<BATCH, CHANNELS, 0, stream>>>(semantic, W1, b1, W2, b2, scale);
    scale_kernel<<<BATCH * CHANNELS, 256, 0, stream>>>(x, scale, out);
}